// Round 18
// baseline (115.544 us; speedup 1.0000x reference)
//
#include <hip/hip_runtime.h>
#include <hip/hip_bf16.h>
#include <hip/hip_fp16.h>

typedef _Float16 f16x8 __attribute__((ext_vector_type(8)));
typedef float f32x4 __attribute__((ext_vector_type(4)));

union B8 { uint4 u; f16x8 h; };

__device__ __forceinline__ float htanh(float v) {
    return fminf(1.f, fmaxf(-1.f, v));
}
__device__ __forceinline__ unsigned short f2h(float f) {
    __half h = __float2half(f);   // RNE; exact for +-1
    return *reinterpret_cast<unsigned short*>(&h);
}
__device__ __forceinline__ float sxor(float h, float w) {
    return __uint_as_float(__float_as_uint(h) ^ (__float_as_uint(w) & 0x80000000u));
}

// Workspace layout (bytes):
//   wsA2 @ 0      : 25*4*64*16 = 102400  (A-frags of sign(w2), fp16)
//   wsA1 @ 102400 : 7*5*64*16  = 35840   (A-frags of sign(w1), fp16)
//   h2   @ 138240 : 2048*400*4 = 3276800
#define WSA1_OFF 102400
#define H2_OFF   138240

// ---------------------------------------------------------------------------
// K-SLOT MAPPING (contiguity + odd-stride banks).  sxu layout [y][c][x37]:
// word = 111y + 37c + x; tap-row rr = 3ky+c at base 37rr.
//   kk<=3 : rr = kk*4+g, kx = r   (4 consecutive words -> 2x ds_read2_b32)
//   kk==4 : rr = s = g*4+r, kx=4
// rr==15 / s==15 are zero slots (A=0); pad holes are READ by them so sxu is
// zeroed in full (round-6: unwritten LDS as fp16 Inf * 0 = NaN).
__global__ __launch_bounds__(256) void bn_pack(
    const float* __restrict__ w1, uint4* __restrict__ wsA1,
    const float* __restrict__ w2, uint4* __restrict__ wsA2)
{
    if (blockIdx.x < 9) {
        int t = blockIdx.x * 256 + threadIdx.x;    // 0..2239 used
        if (t >= 2240) return;
        int lane = t & 63;
        int kk = (t >> 6) % 5;
        int m  = t / 320;
        int oc = m * 16 + (lane & 15), g = lane >> 4;
        unsigned int d[4];
        #pragma unroll
        for (int r = 0; r < 4; ++r) {
            int c, ky, kx; bool tv;
            if (kk < 4) { int rr = kk * 4 + g; tv = rr < 15; c = rr % 3; ky = rr / 3; kx = r; }
            else        { int s  = g * 4 + r;  tv = s  < 15; c = s  % 3; ky = s  / 3; kx = 4; }
            unsigned int v = 0u;
            if (tv && oc < 100) {
                float wv = w1[((oc * 3 + c) * 5 + ky) * 5 + kx];
                unsigned int sg = wv > 0.f ? 0x3C00u : (wv < 0.f ? 0xBC00u : 0u);
                v = sg | (sg << 16);          // same sign in hi-slot and lo-slot
            }
            d[r] = v;
        }
        wsA1[t] = make_uint4(d[0], d[1], d[2], d[3]);
    } else {
        int t = (blockIdx.x - 9) * 256 + threadIdx.x;  // 0..6399
        int lane = t & 63;
        int kk = (t >> 6) & 3;
        int s = t >> 8;
        int oc = lane & 15, g = lane >> 4;
        unsigned int d[4];
        #pragma unroll
        for (int r = 0; r < 4; ++r) {
            unsigned int u[2];
            #pragma unroll
            for (int h = 0; h < 2; ++h) {
                int ic = kk * 32 + g * 8 + r * 2 + h;
                unsigned int v = 0u;
                if (ic < 100) {
                    float wv = w2[(oc * 100 + ic) * 25 + s];
                    v = wv > 0.f ? 0x3C00u : (wv < 0.f ? 0xBC00u : 0u);
                }
                u[h] = v;
            }
            d[r] = u[0] | (u[1] << 16);
        }
        wsA2[t] = make_uint4(d[0], d[1], d[2], d[3]);
    }
}

// ---------------------------------------------------------------------------
// HT SIGMA-LAYOUT: window row (ry,rx) at slot sigma = ry*18 + rx, row stride
// 120 halves.  sigma mod 8 = 2ry+rx increments by exactly 1 per consecutive
// P, so conv2 b128 reads spread evenly over banks (measured: 16.7M -> 13.05M
// conflict cycles).  Holes/tails are read by zero-A slots -> ht zeroed IN
// FULL in phase 0 (round-6: Inf*0=NaN nondeterminism).
// OCCUPANCY LEDGER (r9-13, CLOSED): 2 blocks/CU (~21%), immovable:
//   - (256,3)/min-waves: allocator halves arch-VGPR cap -> spill (r1/r2/r5)
//   - 512-thread blocks: 2x74.75 KB refused co-schedule, +imbalance (r11)
//   - half-image 48.6 KB blocks: 3rd block STILL refused (r13), and
//     runtime-bounded accumulator loops serialized MFMA (37%->21% util)
// ARCH-VGPR / ILP LEDGER (r15/r16, CLOSED): 96 VGPRs is the equilibrium.
// 2-tile pairing spilled (r15); 4-pass acc batching spilled (r16).
// ROUND 18 (T5): s_setprio(1) around MFMA clusters.  Regime check: the two
// co-resident blocks are phase-independent, AND conv1's phase 2 has no
// barriers with per-wave rotated tile starts -> attn-like regime where
// setprio measured +4-7% (m191), not the lockstep-GEMM regime where it was
// neutral/negative (m190).  No register/structure change; bit-identical.
#define HT_HALVES 29952     // max read 29768 < 29952

// conv1 m-group: hi/lo interleaved K, contiguous K-slots, stride-37 sxu,
// sigma-mapped LDS output.
template<int MC>
__device__ __forceinline__ void conv1_group(
    const unsigned int* __restrict__ sxu, const uint4* __restrict__ wsA1,
    const float* b1s, unsigned short* ht, int lane, int g, int col,
    int ntStart, int mBase)
{
    // A-fragments for this m-group: MC*5*4 VGPRs (80 or 60)
    f16x8 a[MC][5];
    #pragma unroll
    for (int mi = 0; mi < MC; ++mi)
        #pragma unroll
        for (int kk = 0; kk < 5; ++kk) {
            B8 t; t.u = wsA1[((mBase + mi) * 5 + kk) * 64 + lane];
            a[mi][kk] = t.h;
        }

    const int g37 = g * 37, g148 = g * 148 + 4;

    for (int nt = ntStart; nt < 13; nt += 4) {
        const int w = nt * 16 + col;            // pool-window id (14x14 row-major)
        const bool valid = w < 196;
        const int wc = valid ? w : 195;
        const int wy = wc / 14, wx = wc - wy * 14;
        const unsigned int* bt = sxu + wy * 222 + wx * 2;
        const unsigned int* b0  = bt + g37;       // main rows (kk stride 148)
        const unsigned int* blx = bt + g148;      // kx=4 leftovers (r stride 37)

        f32x4 mx[MC];
        #pragma unroll
        for (int pass = 0; pass < 4; ++pass) {
            const int q = (pass >> 1) * 111 + (pass & 1);   // qy*111 + qx

            f32x4 acc[MC];
            __builtin_amdgcn_s_setprio(1);      // favor the MFMA chain
            #pragma unroll
            for (int kk = 0; kk < 5; ++kk) {
                B8 bb;
                if (kk < 4) {
                    const unsigned int* bk = b0 + kk * 148;
                    bb.u = make_uint4(bk[q], bk[q + 1], bk[q + 2], bk[q + 3]);
                } else {
                    bb.u = make_uint4(blx[q], blx[q + 37], blx[q + 74], blx[q + 111]);
                }
                #pragma unroll
                for (int mi = 0; mi < MC; ++mi) {
                    f32x4 c0 = (kk == 0) ? (f32x4){0.f, 0.f, 0.f, 0.f} : acc[mi];
                    acc[mi] = __builtin_amdgcn_mfma_f32_16x16x32_f16(a[mi][kk], bb.h, c0, 0, 0, 0);
                }
            }
            __builtin_amdgcn_s_setprio(0);
            #pragma unroll
            for (int mi = 0; mi < MC; ++mi) {
                if (pass == 0) {
                    mx[mi] = acc[mi];
                } else {
                    #pragma unroll
                    for (int r = 0; r < 4; ++r)
                        mx[mi][r] = fmaxf(mx[mi][r], acc[mi][r]);
                }
            }
        }

        if (valid) {
            const int sig = wy * 18 + wx;          // sigma-mapped row slot
            #pragma unroll
            for (int mi = 0; mi < MC; ++mi) {
                const int oc0 = (mBase + mi) * 16 + g * 4;
                if (oc0 < 104) {
                    float4 bias = *(const float4*)&b1s[oc0];
                    unsigned short o0 = f2h(htanh(mx[mi][0] + bias.x));
                    unsigned short o1 = f2h(htanh(mx[mi][1] + bias.y));
                    unsigned short o2 = f2h(htanh(mx[mi][2] + bias.z));
                    unsigned short o3 = f2h(htanh(mx[mi][3] + bias.w));
                    uint2 d;
                    d.x = (unsigned int)o0 | ((unsigned int)o1 << 16);
                    d.y = (unsigned int)o2 | ((unsigned int)o3 << 16);
                    *(uint2*)(ht + sig * 120 + oc0) = d;   // LDS write
                }
            }
        }
    }
}

// ---------------------------------------------------------------------------
// FUSED conv1+conv2, 256 threads (round-12/14 structure + setprio).  One
// block per image: conv1 -> ht (LDS) -> conv2 (K-split by wave) -> partial
// reduce -> pool -> h2.  fc separate (r10: in-block fc cost > saving).
__global__ __launch_bounds__(256, 2) void bn_convs(
    const float* __restrict__ x, const uint4* __restrict__ wsA1,
    const unsigned short* __restrict__ wsA2,
    const float* __restrict__ b1, const float* __restrict__ b2,
    float* __restrict__ h2)
{
    __shared__ __align__(16) unsigned int sxu[3584];        // 14336 B
    __shared__ __align__(16) unsigned short ht[HT_HALVES];  // 59904 B
    __shared__ float b1s[112];
    const int img = blockIdx.x;
    const int tid = threadIdx.x;
    const int lane = tid & 63, wv = tid >> 6;   // 4 waves

    // phase 0: zero sxu + ALL of ht (holes/tails read by zero-A slots)
    {
        uint4* z = (uint4*)sxu;
        for (int i = tid; i < 896; i += 256) z[i] = make_uint4(0u, 0u, 0u, 0u);
        uint4* zh = (uint4*)ht;
        for (int i = tid; i < 3744; i += 256) zh[i] = make_uint4(0u, 0u, 0u, 0u);
    }
    __syncthreads();

    // phase 1: stage x -> interleaved (hi,lo) fp16 per pixel, [y][c][x37]
    {
        const float4* xg = (const float4*)(x + (size_t)img * 3072);
        for (int i = tid; i < 768; i += 256) {
            float4 v = xg[i];
            float vv[4] = {v.x, v.y, v.z, v.w};
            unsigned int u[4];
            #pragma unroll
            for (int q = 0; q < 4; ++q) {
                __half h = __float2half(vv[q]);
                float rs = vv[q] - __half2float(h);
                __half rl = __float2half(rs);
                u[q] = (unsigned int)*(unsigned short*)&h |
                       ((unsigned int)*(unsigned short*)&rl << 16);
            }
            int c = i >> 8, y = (i >> 3) & 31, q4 = i & 7;
            int base = 111 * y + 37 * c + 4 * q4;
            sxu[base]     = u[0];
            sxu[base + 1] = u[1];
            sxu[base + 2] = u[2];
            sxu[base + 3] = u[3];
        }
        if (tid < 112) b1s[tid] = (tid < 100) ? b1[tid] : 0.f;
    }
    __syncthreads();

    const int g = lane >> 4;
    const int col = lane & 15;

    // phase 2: conv1 -> ht (two sequential m-groups; rotated tile start)
    const int s0 = (wv + (img & 3)) & 3;
    conv1_group<4>(sxu, wsA1, b1s, ht, lane, g, col, s0, 0);
    conv1_group<3>(sxu, wsA1, b1s, ht, lane, g, col, s0, 4);
    __syncthreads();   // all conv1 writes visible before conv2 reads

    // phase 3: conv2 MFMA, K-split by wave (kk = wv), sigma-mapped reads
    int bc[7];
    #pragma unroll
    for (int t = 0; t < 7; ++t) {
        int P = t * 16 + col;
        int Pc = P < 100 ? P : 99;
        bc[t] = ((Pc / 10) * 18 + (Pc % 10)) * 120 + g * 8;
    }
    f32x4 acc[7];
    #pragma unroll
    for (int t = 0; t < 7; ++t) acc[t] = (f32x4){0.f, 0.f, 0.f, 0.f};

    const f16x8* wsAv = (const f16x8*)wsA2;
    const int ko = wv * 32;
    {   // taps 0..12  (A in two halves: 52 arch-VGPR peak — no spill)
        f16x8 a2[13];
        #pragma unroll
        for (int j = 0; j < 13; ++j)
            a2[j] = wsAv[((j * 4 + wv) << 6) | lane];
        __builtin_amdgcn_s_setprio(1);
        #pragma unroll
        for (int s = 0; s < 13; ++s) {
            const int off = ((s / 5) * 18 + (s % 5)) * 120 + ko;
            #pragma unroll
            for (int t = 0; t < 7; ++t) {
                f16x8 bb = *(const f16x8*)&ht[bc[t] + off];
                acc[t] = __builtin_amdgcn_mfma_f32_16x16x32_f16(a2[s], bb, acc[t], 0, 0, 0);
            }
        }
        __builtin_amdgcn_s_setprio(0);
    }
    {   // taps 13..24
        f16x8 a2[12];
        #pragma unroll
        for (int j = 0; j < 12; ++j)
            a2[j] = wsAv[(((13 + j) * 4 + wv) << 6) | lane];
        __builtin_amdgcn_s_setprio(1);
        #pragma unroll
        for (int s = 13; s < 25; ++s) {
            const int off = ((s / 5) * 18 + (s % 5)) * 120 + ko;
            #pragma unroll
            for (int t = 0; t < 7; ++t) {
                f16x8 bb = *(const f16x8*)&ht[bc[t] + off];
                acc[t] = __builtin_amdgcn_mfma_f32_16x16x32_f16(a2[s - 13], bb, acc[t], 0, 0, 0);
            }
        }
        __builtin_amdgcn_s_setprio(0);
    }
    __syncthreads();   // all waves done reading ht -> safe to overlay partials

    // phase 4: per-kk partials pc[kk][t][oc][col] overlaid on ht
    float* pc = (float*)ht;               // 4*7*16*16 floats = 28672 B
    #pragma unroll
    for (int t = 0; t < 7; ++t)
        #pragma unroll
        for (int r = 0; r < 4; ++r)
            pc[(((wv * 7 + t) * 16) + (g * 4 + r)) * 16 + col] = acc[t][r];
    __syncthreads();

    // phase 5: reduce 4 partials + bias + hardtanh -> y[oc][P]
    float* y = (float*)ht + 7168;         // 16*100 floats
    for (int i = tid; i < 1792; i += 256) {
        int t = i >> 8, rem = i & 255;
        int oc = rem >> 4, c2 = rem & 15;
        int P = t * 16 + c2;
        if (P < 100) {
            int idx = (t * 16 + oc) * 16 + c2;
            float v = pc[idx] + pc[1792 + idx] + pc[3584 + idx] + pc[5376 + idx];
            y[oc * 100 + P] = htanh(v + b2[oc]);
        }
    }
    __syncthreads();

    // phase 6: maxpool 2x2 over the 10x10 grid -> h2[img][oc*25 + pp]
    for (int t2i = tid; t2i < 400; t2i += 256) {
        int oc = t2i / 25, pp = t2i - oc * 25;
        int ppy = pp / 5, ppx = pp - ppy * 5;
        int base = oc * 100 + ppy * 20 + ppx * 2;
        float m = fmaxf(fmaxf(y[base], y[base + 1]),
                        fmaxf(y[base + 10], y[base + 11]));
        h2[(size_t)img * 400 + t2i] = m;
    }
}

// ---------------------------------------------------------------------------
// fc1 -> hardtanh -> fc2 -> hardtanh -> fc3.  1024 blocks x 2 images
// (4 blocks/CU — more TLP for this latency-bound tail).
__global__ __launch_bounds__(256) void bn_fc(
    const float* __restrict__ h2,
    const float* __restrict__ w3, const float* __restrict__ b3,
    const float* __restrict__ w4, const float* __restrict__ b4,
    const float* __restrict__ w5, const float* __restrict__ b5,
    float* __restrict__ out)
{
    __shared__ float sh2[2 * 404];
    __shared__ float sh3[2 * 124];
    __shared__ float sh4[2 * 88];
    const int b0 = blockIdx.x * 2;
    const int tid = threadIdx.x;

    for (int i = tid; i < 800; i += 256) {
        int s = i / 400, k = i - s * 400;
        sh2[s * 404 + k] = h2[(size_t)(b0 + s) * 400 + k];
    }
    __syncthreads();

    for (int t = tid; t < 240; t += 256) {
        int o = t >> 1, s = t & 1;
        const float4* wr = (const float4*)(w3 + o * 400);
        const float4* hr = (const float4*)&sh2[s * 404];
        float a0 = 0.f, a1 = 0.f, a2 = 0.f, a3 = 0.f;
        #pragma unroll 5
        for (int k = 0; k < 100; ++k) {
            float4 w = wr[k], h = hr[k];
            a0 += sxor(h.x, w.x); a1 += sxor(h.y, w.y);
            a2 += sxor(h.z, w.z); a3 += sxor(h.w, w.w);
        }
        sh3[s * 124 + o] = htanh(b3[o] + ((a0 + a1) + (a2 + a3)));
    }
    __syncthreads();

    for (int t = tid; t < 168; t += 256) {
        int o = t >> 1, s = t & 1;
        const float4* wr = (const float4*)(w4 + o * 120);
        const float4* hr = (const float4*)&sh3[s * 124];
        float a0 = 0.f, a1 = 0.f, a2 = 0.f, a3 = 0.f;
        #pragma unroll
        for (int k = 0; k < 30; ++k) {
            float4 w = wr[k], h = hr[k];
            a0 += sxor(h.x, w.x); a1 += sxor(h.y, w.y);
            a2 += sxor(h.z, w.z); a3 += sxor(h.w, w.w);
        }
        sh4[s * 88 + o] = htanh(b4[o] + ((a0 + a1) + (a2 + a3)));
    }
    __syncthreads();

    for (int t = tid; t < 20; t += 256) {
        int o = t >> 1, s = t & 1;
        const float4* wr = (const float4*)(w5 + o * 84);
        const float4* hr = (const float4*)&sh4[s * 88];
        float a0 = 0.f, a1 = 0.f, a2 = 0.f, a3 = 0.f;
        #pragma unroll
        for (int k = 0; k < 21; ++k) {
            float4 w = wr[k], h = hr[k];
            a0 += sxor(h.x, w.x); a1 += sxor(h.y, w.y);
            a2 += sxor(h.z, w.z); a3 += sxor(h.w, w.w);
        }
        out[(size_t)(b0 + s) * 10 + o] = b5[o] + ((a0 + a1) + (a2 + a3));
    }
}

extern "C" void kernel_launch(void* const* d_in, const int* in_sizes, int n_in,
                              void* d_out, int out_size, void* d_ws, size_t ws_size,
                              hipStream_t stream) {
    const float* x  = (const float*)d_in[0];
    const float* w1 = (const float*)d_in[1];
    const float* b1 = (const float*)d_in[2];
    const float* w2 = (const float*)d_in[3];
    const float* b2 = (const float*)d_in[4];
    const float* w3 = (const float*)d_in[5];
    const float* b3 = (const float*)d_in[6];
    const float* w4 = (const float*)d_in[7];
    const float* b4 = (const float*)d_in[8];
    const float* w5 = (const float*)d_in[9];
    const float* b5 = (const float*)d_in[10];
    float* out = (float*)d_out;

    unsigned short* wsA2 = (unsigned short*)d_ws;
    uint4* wsA1          = (uint4*)((char*)d_ws + WSA1_OFF);
    float* h2            = (float*)((char*)d_ws + H2_OFF);

    hipLaunchKernelGGL(bn_pack, dim3(34), dim3(256), 0, stream,
                       w1, wsA1, w2, (uint4*)wsA2);
    hipLaunchKernelGGL(bn_convs, dim3(2048), dim3(256), 0, stream,
                       x, wsA1, wsA2, b1, b2, h2);
    hipLaunchKernelGGL(bn_fc, dim3(1024), dim3(256), 0, stream, h2,
                       w3, b3, w4, b4, w5, b5, out);
}

// Round 19
// 110.694 us; speedup vs baseline: 1.0438x; 1.0438x over previous
//
#include <hip/hip_runtime.h>
#include <hip/hip_bf16.h>
#include <hip/hip_fp16.h>

typedef _Float16 f16x8 __attribute__((ext_vector_type(8)));
typedef float f32x4 __attribute__((ext_vector_type(4)));

union B8 { uint4 u; f16x8 h; };

__device__ __forceinline__ float htanh(float v) {
    return fminf(1.f, fmaxf(-1.f, v));
}
__device__ __forceinline__ unsigned short f2h(float f) {
    __half h = __float2half(f);   // RNE; exact for +-1
    return *reinterpret_cast<unsigned short*>(&h);
}
__device__ __forceinline__ float sxor(float h, float w) {
    return __uint_as_float(__float_as_uint(h) ^ (__float_as_uint(w) & 0x80000000u));
}

// Workspace layout (bytes):
//   wsA2 @ 0      : 25*4*64*16 = 102400  (A-frags of sign(w2), fp16)
//   wsA1 @ 102400 : 7*5*64*16  = 35840   (A-frags of sign(w1), fp16)
//   h2   @ 138240 : 2048*400*4 = 3276800
#define WSA1_OFF 102400
#define H2_OFF   138240

// ---------------------------------------------------------------------------
// K-SLOT MAPPING (contiguity + odd-stride banks).  sxu layout [y][c][x37]:
// word = 111y + 37c + x; tap-row rr = 3ky+c at base 37rr.
//   kk<=3 : rr = kk*4+g, kx = r   (4 consecutive words -> 2x ds_read2_b32)
//   kk==4 : rr = s = g*4+r, kx=4
// rr==15 / s==15 are zero slots (A=0); pad holes are READ by them so sxu is
// zeroed in full (round-6: unwritten LDS as fp16 Inf * 0 = NaN).
__global__ __launch_bounds__(256) void bn_pack(
    const float* __restrict__ w1, uint4* __restrict__ wsA1,
    const float* __restrict__ w2, uint4* __restrict__ wsA2)
{
    if (blockIdx.x < 9) {
        int t = blockIdx.x * 256 + threadIdx.x;    // 0..2239 used
        if (t >= 2240) return;
        int lane = t & 63;
        int kk = (t >> 6) % 5;
        int m  = t / 320;
        int oc = m * 16 + (lane & 15), g = lane >> 4;
        unsigned int d[4];
        #pragma unroll
        for (int r = 0; r < 4; ++r) {
            int c, ky, kx; bool tv;
            if (kk < 4) { int rr = kk * 4 + g; tv = rr < 15; c = rr % 3; ky = rr / 3; kx = r; }
            else        { int s  = g * 4 + r;  tv = s  < 15; c = s  % 3; ky = s  / 3; kx = 4; }
            unsigned int v = 0u;
            if (tv && oc < 100) {
                float wv = w1[((oc * 3 + c) * 5 + ky) * 5 + kx];
                unsigned int sg = wv > 0.f ? 0x3C00u : (wv < 0.f ? 0xBC00u : 0u);
                v = sg | (sg << 16);          // same sign in hi-slot and lo-slot
            }
            d[r] = v;
        }
        wsA1[t] = make_uint4(d[0], d[1], d[2], d[3]);
    } else {
        int t = (blockIdx.x - 9) * 256 + threadIdx.x;  // 0..6399
        int lane = t & 63;
        int kk = (t >> 6) & 3;
        int s = t >> 8;
        int oc = lane & 15, g = lane >> 4;
        unsigned int d[4];
        #pragma unroll
        for (int r = 0; r < 4; ++r) {
            unsigned int u[2];
            #pragma unroll
            for (int h = 0; h < 2; ++h) {
                int ic = kk * 32 + g * 8 + r * 2 + h;
                unsigned int v = 0u;
                if (ic < 100) {
                    float wv = w2[(oc * 100 + ic) * 25 + s];
                    v = wv > 0.f ? 0x3C00u : (wv < 0.f ? 0xBC00u : 0u);
                }
                u[h] = v;
            }
            d[r] = u[0] | (u[1] << 16);
        }
        wsA2[t] = make_uint4(d[0], d[1], d[2], d[3]);
    }
}

// ---------------------------------------------------------------------------
// HT SIGMA-LAYOUT: window row (ry,rx) at slot sigma = ry*18 + rx, row stride
// 120 halves.  sigma mod 8 = 2ry+rx increments by exactly 1 per consecutive
// P, so conv2 b128 reads spread evenly over banks (measured: 16.7M -> 13.05M
// conflict cycles).  Holes/tails are read by zero-A slots -> ht zeroed IN
// FULL in phase 0 (round-6: Inf*0=NaN nondeterminism).
// FINAL LEDGER (18 rounds):
//   Occupancy (CLOSED): 2 blocks/CU immovable — (256,3)/min-waves halves the
//     arch-VGPR cap -> spill (r1/r2/r5); 512-thread refused co-schedule
//     (r11); 48.6 KB half-image blocks refused a 3rd block (r13).
//   Arch-VGPR/ILP (CLOSED): 96 VGPRs is the equilibrium; 2-tile pairing
//     (r15) and 4-pass acc batching (r16) both spilled at the ~128 ceiling.
//   setprio/T5 (CLOSED): regressed +3 µs (r18) — perturbed codegen (VGPR
//     96->88, conflicts 13->16.6M); this is the lockstep-GEMM regime.
//   fc fusion (CLOSED): +10 µs in-kernel vs ~21 µs saved (r10).
// Best reproducible state: this file — 110.8-110.9 µs (r14/r17).
#define HT_HALVES 29952     // max read 29768 < 29952

// conv1 m-group: hi/lo interleaved K, contiguous K-slots, stride-37 sxu,
// sigma-mapped LDS output.
template<int MC>
__device__ __forceinline__ void conv1_group(
    const unsigned int* __restrict__ sxu, const uint4* __restrict__ wsA1,
    const float* b1s, unsigned short* ht, int lane, int g, int col,
    int ntStart, int mBase)
{
    // A-fragments for this m-group: MC*5*4 VGPRs (80 or 60)
    f16x8 a[MC][5];
    #pragma unroll
    for (int mi = 0; mi < MC; ++mi)
        #pragma unroll
        for (int kk = 0; kk < 5; ++kk) {
            B8 t; t.u = wsA1[((mBase + mi) * 5 + kk) * 64 + lane];
            a[mi][kk] = t.h;
        }

    const int g37 = g * 37, g148 = g * 148 + 4;

    for (int nt = ntStart; nt < 13; nt += 4) {
        const int w = nt * 16 + col;            // pool-window id (14x14 row-major)
        const bool valid = w < 196;
        const int wc = valid ? w : 195;
        const int wy = wc / 14, wx = wc - wy * 14;
        const unsigned int* bt = sxu + wy * 222 + wx * 2;
        const unsigned int* b0  = bt + g37;       // main rows (kk stride 148)
        const unsigned int* blx = bt + g148;      // kx=4 leftovers (r stride 37)

        f32x4 mx[MC];
        #pragma unroll
        for (int pass = 0; pass < 4; ++pass) {
            const int q = (pass >> 1) * 111 + (pass & 1);   // qy*111 + qx

            f32x4 acc[MC];
            #pragma unroll
            for (int kk = 0; kk < 5; ++kk) {
                B8 bb;
                if (kk < 4) {
                    const unsigned int* bk = b0 + kk * 148;
                    bb.u = make_uint4(bk[q], bk[q + 1], bk[q + 2], bk[q + 3]);
                } else {
                    bb.u = make_uint4(blx[q], blx[q + 37], blx[q + 74], blx[q + 111]);
                }
                #pragma unroll
                for (int mi = 0; mi < MC; ++mi) {
                    f32x4 c0 = (kk == 0) ? (f32x4){0.f, 0.f, 0.f, 0.f} : acc[mi];
                    acc[mi] = __builtin_amdgcn_mfma_f32_16x16x32_f16(a[mi][kk], bb.h, c0, 0, 0, 0);
                }
            }
            #pragma unroll
            for (int mi = 0; mi < MC; ++mi) {
                if (pass == 0) {
                    mx[mi] = acc[mi];
                } else {
                    #pragma unroll
                    for (int r = 0; r < 4; ++r)
                        mx[mi][r] = fmaxf(mx[mi][r], acc[mi][r]);
                }
            }
        }

        if (valid) {
            const int sig = wy * 18 + wx;          // sigma-mapped row slot
            #pragma unroll
            for (int mi = 0; mi < MC; ++mi) {
                const int oc0 = (mBase + mi) * 16 + g * 4;
                if (oc0 < 104) {
                    float4 bias = *(const float4*)&b1s[oc0];
                    unsigned short o0 = f2h(htanh(mx[mi][0] + bias.x));
                    unsigned short o1 = f2h(htanh(mx[mi][1] + bias.y));
                    unsigned short o2 = f2h(htanh(mx[mi][2] + bias.z));
                    unsigned short o3 = f2h(htanh(mx[mi][3] + bias.w));
                    uint2 d;
                    d.x = (unsigned int)o0 | ((unsigned int)o1 << 16);
                    d.y = (unsigned int)o2 | ((unsigned int)o3 << 16);
                    *(uint2*)(ht + sig * 120 + oc0) = d;   // LDS write
                }
            }
        }
    }
}

// ---------------------------------------------------------------------------
// FUSED conv1+conv2, 256 threads (round-12/14 configuration — measured best:
// bn_convs ~93 µs, total 110.8 µs).  One block per image: conv1 -> ht
// (LDS) -> conv2 (K-split by wave, compile-time 7-tile unroll) -> partial
// reduce -> pool -> h2.  fc separate (r10: in-block fc cost > saving).
__global__ __launch_bounds__(256, 2) void bn_convs(
    const float* __restrict__ x, const uint4* __restrict__ wsA1,
    const unsigned short* __restrict__ wsA2,
    const float* __restrict__ b1, const float* __restrict__ b2,
    float* __restrict__ h2)
{
    __shared__ __align__(16) unsigned int sxu[3584];        // 14336 B
    __shared__ __align__(16) unsigned short ht[HT_HALVES];  // 59904 B
    __shared__ float b1s[112];
    const int img = blockIdx.x;
    const int tid = threadIdx.x;
    const int lane = tid & 63, wv = tid >> 6;   // 4 waves

    // phase 0: zero sxu + ALL of ht (holes/tails read by zero-A slots)
    {
        uint4* z = (uint4*)sxu;
        for (int i = tid; i < 896; i += 256) z[i] = make_uint4(0u, 0u, 0u, 0u);
        uint4* zh = (uint4*)ht;
        for (int i = tid; i < 3744; i += 256) zh[i] = make_uint4(0u, 0u, 0u, 0u);
    }
    __syncthreads();

    // phase 1: stage x -> interleaved (hi,lo) fp16 per pixel, [y][c][x37]
    {
        const float4* xg = (const float4*)(x + (size_t)img * 3072);
        for (int i = tid; i < 768; i += 256) {
            float4 v = xg[i];
            float vv[4] = {v.x, v.y, v.z, v.w};
            unsigned int u[4];
            #pragma unroll
            for (int q = 0; q < 4; ++q) {
                __half h = __float2half(vv[q]);
                float rs = vv[q] - __half2float(h);
                __half rl = __float2half(rs);
                u[q] = (unsigned int)*(unsigned short*)&h |
                       ((unsigned int)*(unsigned short*)&rl << 16);
            }
            int c = i >> 8, y = (i >> 3) & 31, q4 = i & 7;
            int base = 111 * y + 37 * c + 4 * q4;
            sxu[base]     = u[0];
            sxu[base + 1] = u[1];
            sxu[base + 2] = u[2];
            sxu[base + 3] = u[3];
        }
        if (tid < 112) b1s[tid] = (tid < 100) ? b1[tid] : 0.f;
    }
    __syncthreads();

    const int g = lane >> 4;
    const int col = lane & 15;

    // phase 2: conv1 -> ht (two sequential m-groups; rotated tile start)
    const int s0 = (wv + (img & 3)) & 3;
    conv1_group<4>(sxu, wsA1, b1s, ht, lane, g, col, s0, 0);
    conv1_group<3>(sxu, wsA1, b1s, ht, lane, g, col, s0, 4);
    __syncthreads();   // all conv1 writes visible before conv2 reads

    // phase 3: conv2 MFMA, K-split by wave (kk = wv), sigma-mapped reads
    int bc[7];
    #pragma unroll
    for (int t = 0; t < 7; ++t) {
        int P = t * 16 + col;
        int Pc = P < 100 ? P : 99;
        bc[t] = ((Pc / 10) * 18 + (Pc % 10)) * 120 + g * 8;
    }
    f32x4 acc[7];
    #pragma unroll
    for (int t = 0; t < 7; ++t) acc[t] = (f32x4){0.f, 0.f, 0.f, 0.f};

    const f16x8* wsAv = (const f16x8*)wsA2;
    const int ko = wv * 32;
    {   // taps 0..12  (A in two halves: 52 arch-VGPR peak — no spill)
        f16x8 a2[13];
        #pragma unroll
        for (int j = 0; j < 13; ++j)
            a2[j] = wsAv[((j * 4 + wv) << 6) | lane];
        #pragma unroll
        for (int s = 0; s < 13; ++s) {
            const int off = ((s / 5) * 18 + (s % 5)) * 120 + ko;
            #pragma unroll
            for (int t = 0; t < 7; ++t) {
                f16x8 bb = *(const f16x8*)&ht[bc[t] + off];
                acc[t] = __builtin_amdgcn_mfma_f32_16x16x32_f16(a2[s], bb, acc[t], 0, 0, 0);
            }
        }
    }
    {   // taps 13..24
        f16x8 a2[12];
        #pragma unroll
        for (int j = 0; j < 12; ++j)
            a2[j] = wsAv[(((13 + j) * 4 + wv) << 6) | lane];
        #pragma unroll
        for (int s = 13; s < 25; ++s) {
            const int off = ((s / 5) * 18 + (s % 5)) * 120 + ko;
            #pragma unroll
            for (int t = 0; t < 7; ++t) {
                f16x8 bb = *(const f16x8*)&ht[bc[t] + off];
                acc[t] = __builtin_amdgcn_mfma_f32_16x16x32_f16(a2[s - 13], bb, acc[t], 0, 0, 0);
            }
        }
    }
    __syncthreads();   // all waves done reading ht -> safe to overlay partials

    // phase 4: per-kk partials pc[kk][t][oc][col] overlaid on ht
    float* pc = (float*)ht;               // 4*7*16*16 floats = 28672 B
    #pragma unroll
    for (int t = 0; t < 7; ++t)
        #pragma unroll
        for (int r = 0; r < 4; ++r)
            pc[(((wv * 7 + t) * 16) + (g * 4 + r)) * 16 + col] = acc[t][r];
    __syncthreads();

    // phase 5: reduce 4 partials + bias + hardtanh -> y[oc][P]
    float* y = (float*)ht + 7168;         // 16*100 floats
    for (int i = tid; i < 1792; i += 256) {
        int t = i >> 8, rem = i & 255;
        int oc = rem >> 4, c2 = rem & 15;
        int P = t * 16 + c2;
        if (P < 100) {
            int idx = (t * 16 + oc) * 16 + c2;
            float v = pc[idx] + pc[1792 + idx] + pc[3584 + idx] + pc[5376 + idx];
            y[oc * 100 + P] = htanh(v + b2[oc]);
        }
    }
    __syncthreads();

    // phase 6: maxpool 2x2 over the 10x10 grid -> h2[img][oc*25 + pp]
    for (int t2i = tid; t2i < 400; t2i += 256) {
        int oc = t2i / 25, pp = t2i - oc * 25;
        int ppy = pp / 5, ppx = pp - ppy * 5;
        int base = oc * 100 + ppy * 20 + ppx * 2;
        float m = fmaxf(fmaxf(y[base], y[base + 1]),
                        fmaxf(y[base + 10], y[base + 11]));
        h2[(size_t)img * 400 + t2i] = m;
    }
}

// ---------------------------------------------------------------------------
// fc1 -> hardtanh -> fc2 -> hardtanh -> fc3.  1024 blocks x 2 images
// (4 blocks/CU — more TLP for this latency-bound tail).
__global__ __launch_bounds__(256) void bn_fc(
    const float* __restrict__ h2,
    const float* __restrict__ w3, const float* __restrict__ b3,
    const float* __restrict__ w4, const float* __restrict__ b4,
    const float* __restrict__ w5, const float* __restrict__ b5,
    float* __restrict__ out)
{
    __shared__ float sh2[2 * 404];
    __shared__ float sh3[2 * 124];
    __shared__ float sh4[2 * 88];
    const int b0 = blockIdx.x * 2;
    const int tid = threadIdx.x;

    for (int i = tid; i < 800; i += 256) {
        int s = i / 400, k = i - s * 400;
        sh2[s * 404 + k] = h2[(size_t)(b0 + s) * 400 + k];
    }
    __syncthreads();

    for (int t = tid; t < 240; t += 256) {
        int o = t >> 1, s = t & 1;
        const float4* wr = (const float4*)(w3 + o * 400);
        const float4* hr = (const float4*)&sh2[s * 404];
        float a0 = 0.f, a1 = 0.f, a2 = 0.f, a3 = 0.f;
        #pragma unroll 5
        for (int k = 0; k < 100; ++k) {
            float4 w = wr[k], h = hr[k];
            a0 += sxor(h.x, w.x); a1 += sxor(h.y, w.y);
            a2 += sxor(h.z, w.z); a3 += sxor(h.w, w.w);
        }
        sh3[s * 124 + o] = htanh(b3[o] + ((a0 + a1) + (a2 + a3)));
    }
    __syncthreads();

    for (int t = tid; t < 168; t += 256) {
        int o = t >> 1, s = t & 1;
        const float4* wr = (const float4*)(w4 + o * 120);
        const float4* hr = (const float4*)&sh3[s * 124];
        float a0 = 0.f, a1 = 0.f, a2 = 0.f, a3 = 0.f;
        #pragma unroll
        for (int k = 0; k < 30; ++k) {
            float4 w = wr[k], h = hr[k];
            a0 += sxor(h.x, w.x); a1 += sxor(h.y, w.y);
            a2 += sxor(h.z, w.z); a3 += sxor(h.w, w.w);
        }
        sh4[s * 88 + o] = htanh(b4[o] + ((a0 + a1) + (a2 + a3)));
    }
    __syncthreads();

    for (int t = tid; t < 20; t += 256) {
        int o = t >> 1, s = t & 1;
        const float4* wr = (const float4*)(w5 + o * 84);
        const float4* hr = (const float4*)&sh4[s * 88];
        float a0 = 0.f, a1 = 0.f, a2 = 0.f, a3 = 0.f;
        #pragma unroll
        for (int k = 0; k < 21; ++k) {
            float4 w = wr[k], h = hr[k];
            a0 += sxor(h.x, w.x); a1 += sxor(h.y, w.y);
            a2 += sxor(h.z, w.z); a3 += sxor(h.w, w.w);
        }
        out[(size_t)(b0 + s) * 10 + o] = b5[o] + ((a0 + a1) + (a2 + a3));
    }
}

extern "C" void kernel_launch(void* const* d_in, const int* in_sizes, int n_in,
                              void* d_out, int out_size, void* d_ws, size_t ws_size,
                              hipStream_t stream) {
    const float* x  = (const float*)d_in[0];
    const float* w1 = (const float*)d_in[1];
    const float* b1 = (const float*)d_in[2];
    const float* w2 = (const float*)d_in[3];
    const float* b2 = (const float*)d_in[4];
    const float* w3 = (const float*)d_in[5];
    const float* b3 = (const float*)d_in[6];
    const float* w4 = (const float*)d_in[7];
    const float* b4 = (const float*)d_in[8];
    const float* w5 = (const float*)d_in[9];
    const float* b5 = (const float*)d_in[10];
    float* out = (float*)d_out;

    unsigned short* wsA2 = (unsigned short*)d_ws;
    uint4* wsA1          = (uint4*)((char*)d_ws + WSA1_OFF);
    float* h2            = (float*)((char*)d_ws + H2_OFF);

    hipLaunchKernelGGL(bn_pack, dim3(34), dim3(256), 0, stream,
                       w1, wsA1, w2, (uint4*)wsA2);
    hipLaunchKernelGGL(bn_convs, dim3(2048), dim3(256), 0, stream,
                       x, wsA1, wsA2, b1, b2, h2);
    hipLaunchKernelGGL(bn_fc, dim3(1024), dim3(256), 0, stream, h2,
                       w3, b3, w4, b4, w5, b5, out);
}